// Round 2
// baseline (856.246 us; speedup 1.0000x reference)
//
#include <hip/hip_runtime.h>
#include <math.h>

#define NUM_USERS 100000
#define NUM_ITEMS 50000
#define NN 150000
#define DD 64
#define EE 1250000
#define SS 400000
#define TAU 0.2f
#define EDGE_BIAS 0.5f
#define NB_SCAN 586   // ceil(NN/256)
#define NBUCKET 586   // coarse sort buckets (row >> 8)

typedef __attribute__((ext_vector_type(8))) _Float16 f16x8;
typedef __attribute__((ext_vector_type(2))) _Float16 f16x2;
typedef __attribute__((ext_vector_type(4))) float f32x4;

#define LDW 136  // f16 LDS row stride for gate kernel

// bf16 helpers (RNE, finite inputs)
__device__ __forceinline__ unsigned int pack_bf16(float lo, float hi) {
    unsigned int a = __float_as_uint(lo), b = __float_as_uint(hi);
    a += 0x7fffu + ((a >> 16) & 1u);
    b += 0x7fffu + ((b >> 16) & 1u);
    return (a >> 16) | (b & 0xffff0000u);
}
__device__ __forceinline__ float bf_lo(unsigned int u) { return __uint_as_float(u << 16); }
__device__ __forceinline__ float bf_hi(unsigned int u) { return __uint_as_float(u & 0xffff0000u); }

// ---------------------------------------------------------------------------
// init: z0[n][d] = bf16 pair of ego[n][2(d&31)], both chains identical at l=0.
// Also: f16 copy of ego for the gate gather, winner=-1, deg=0, gate_sum=0.
// ---------------------------------------------------------------------------
__global__ void init_kernel(const float* __restrict__ user, const float* __restrict__ item,
                            unsigned int* __restrict__ z0, _Float16* __restrict__ ego16,
                            int* __restrict__ winner, int* __restrict__ deg,
                            double* __restrict__ gate_sum) {
    int j = blockIdx.x * blockDim.x + threadIdx.x;
    if (j < NN * DD) {
        int n = j >> 6, d = j & 63, dp = d & 31;
        const float* ego = (n < NUM_USERS) ? user + (size_t)n * 64
                                           : item + (size_t)(n - NUM_USERS) * 64;
        float2 e = *(const float2*)(ego + 2 * dp);
        z0[j] = pack_bf16(e.x, e.y);
        if (d < 32) {
            f16x2 h;
            h[0] = (_Float16)e.x;
            h[1] = (_Float16)e.y;
            *(f16x2*)(ego16 + (size_t)n * 64 + 2 * dp) = h;
        }
    }
    if (j < EE) winner[j] = -1;
    if (j < NN) deg[j] = 0;
    if (j == 0) *gate_sum = 0.0;
}

// ---------------------------------------------------------------------------
// gate MLP via f16 MFMA (unchanged from round 1)
// ---------------------------------------------------------------------------
__global__ __launch_bounds__(256) void gate_kernel(
        const _Float16* __restrict__ ego16,
        const int* __restrict__ rows, const int* __restrict__ cols,
        const int* __restrict__ sidx, const float* __restrict__ eps,
        const float* __restrict__ W1, const float* __restrict__ b1,
        const float* __restrict__ W2, const float* __restrict__ b2,
        float* __restrict__ gate, double* __restrict__ gate_sum) {
    __shared__ _Float16 sh[64 * LDW];
    __shared__ double sdq[4];

    const int t    = threadIdx.x;
    const int lane = t & 63;
    const int w    = t >> 6;
    const int col  = lane & 15;
    const int quad = lane >> 4;

    for (int idx = t; idx < 8192; idx += 256) {
        int k = idx >> 6, n = idx & 63;
        sh[n * LDW + k] = (_Float16)W1[idx];
    }
    float b1v[4];
#pragma unroll
    for (int nt = 0; nt < 4; ++nt) b1v[nt] = b1[nt * 16 + col];
    float w2v[4];
#pragma unroll
    for (int nt = 0; nt < 4; ++nt) w2v[nt] = W2[nt * 16 + col];
    const float b2v = b2[0];
    __syncthreads();

    f16x8 bfrag[4][4];
#pragma unroll
    for (int nt = 0; nt < 4; ++nt)
#pragma unroll
        for (int kk = 0; kk < 4; ++kk)
            bfrag[nt][kk] = *(const f16x8*)&sh[(nt * 16 + col) * LDW + kk * 32 + quad * 8];

    double partial = 0.0;
    const int sloc = t >> 2;
    const int part = t & 3;

    for (int tile = blockIdx.x; tile < SS / 64; tile += gridDim.x) {
        const int s0 = tile * 64;
        __syncthreads();
        {
            const int s = s0 + sloc;
            const int e = sidx[s];
            const int node = (part < 2) ? rows[e] : cols[e];
            const f16x8* s8 = (const f16x8*)(ego16 + (size_t)node * 64 + (part & 1) * 32);
            f16x8* dst = (f16x8*)&sh[sloc * LDW + part * 32];
#pragma unroll
            for (int h = 0; h < 4; ++h) dst[h] = s8[h];
        }
        __syncthreads();

        f32x4 acc[4] = {};
        const _Float16* abase = &sh[(w * 16 + col) * LDW + quad * 8];
#pragma unroll
        for (int kk = 0; kk < 4; ++kk) {
            f16x8 a = *(const f16x8*)(abase + kk * 32);
#pragma unroll
            for (int nt = 0; nt < 4; ++nt)
                acc[nt] = __builtin_amdgcn_mfma_f32_16x16x32_f16(a, bfrag[nt][kk], acc[nt], 0, 0, 0);
        }

        float p[4];
#pragma unroll
        for (int r = 0; r < 4; ++r) {
            float sum = 0.f;
#pragma unroll
            for (int nt = 0; nt < 4; ++nt)
                sum = fmaf(fmaxf(acc[nt][r] + b1v[nt], 0.f), w2v[nt], sum);
#pragma unroll
            for (int off = 8; off >= 1; off >>= 1) sum += __shfl_xor(sum, off);
            p[r] = sum + b2v;
        }
        if (col == 0) {
            const int sb = s0 + w * 16 + quad * 4;
            float4 ev4 = *(const float4*)(eps + sb);
            float g4[4];
            const float evs[4] = {ev4.x, ev4.y, ev4.z, ev4.w};
#pragma unroll
            for (int r = 0; r < 4; ++r) {
                float ev  = evs[r] * (1.f - 2e-6f) + 1e-6f;
                float gum = logf(ev) - log1pf(-ev);
                float z   = (p[r] + gum) * (1.f / TAU);
                float g   = 1.f / (1.f + expf(-z)) + EDGE_BIAS;
                g4[r] = g;
                partial += (double)g;
            }
            *(float4*)(gate + sb) = make_float4(g4[0], g4[1], g4[2], g4[3]);
        }
    }

#pragma unroll
    for (int off = 32; off >= 1; off >>= 1) partial += __shfl_xor(partial, off);
    if (lane == 0) sdq[w] = partial;
    __syncthreads();
    if (t == 0) atomicAdd(gate_sum, sdq[0] + sdq[1] + sdq[2] + sdq[3]);
}

// ---------------------------------------------------------------------------
// fused winner (last-write-wins) + degree histogram
// ---------------------------------------------------------------------------
__global__ void whist_kernel(const int* __restrict__ rows, const int* __restrict__ sidx,
                             int* __restrict__ deg, int* __restrict__ winner) {
    int e = blockIdx.x * blockDim.x + threadIdx.x;
    if (e < EE) atomicAdd(&deg[rows[e]], 1);
    if (e < SS) atomicMax(&winner[sidx[e]], e);
}

// ---------------------------------------------------------------------------
// CSR build: scan of degree histogram
// ---------------------------------------------------------------------------
__global__ void scan1_kernel(const int* __restrict__ deg, int* __restrict__ rowptr,
                             int* __restrict__ bsum) {
    __shared__ int sh[256];
    int tid = threadIdx.x;
    int i = blockIdx.x * 256 + tid;
    int v = (i < NN) ? deg[i] : 0;
    sh[tid] = v;
    __syncthreads();
    for (int off = 1; off < 256; off <<= 1) {
        int t = (tid >= off) ? sh[tid - off] : 0;
        __syncthreads();
        sh[tid] += t;
        __syncthreads();
    }
    if (i < NN) rowptr[i] = sh[tid] - v;
    if (tid == 255) bsum[blockIdx.x] = sh[255];
}

__global__ void scan2_kernel(int* __restrict__ bsum) {
    __shared__ int sh[1024];
    int tid = threadIdx.x;
    int v = (tid < NB_SCAN) ? bsum[tid] : 0;
    sh[tid] = v;
    __syncthreads();
    for (int off = 1; off < 1024; off <<= 1) {
        int t = (tid >= off) ? sh[tid - off] : 0;
        __syncthreads();
        sh[tid] += t;
        __syncthreads();
    }
    if (tid < NB_SCAN) bsum[tid] = sh[tid] - v;
}

__global__ void scan3_kernel(int* __restrict__ rowptr, const int* __restrict__ bsum,
                             int* __restrict__ ccur) {
    int i = blockIdx.x * blockDim.x + threadIdx.x;
    if (i < NN) rowptr[i] += bsum[i >> 8];
    if (i < NBUCKET) ccur[i] = 0;
    if (i == 0) rowptr[NN] = EE;
}

// ---------------------------------------------------------------------------
// Two-pass bucketed scatter (replaces single-pass 150K-bin scatter whose
// random 16B writes caused 4x write amplification: 79MB WRITE for 20MB data).
//
// pass1: coarse scatter by row>>8 into 586 buckets. Bucket b's staging range
// is [rowptr[b<<8], rowptr[(b+1)<<8]) — contiguous CSR sub-range, no extra
// scan. Active write window = 586 partial lines (~37KB) -> coalesces in L2.
// Payload {row, col, val, mval}; mval computed inline.
// ---------------------------------------------------------------------------
__global__ void scatter_pass1_kernel(
        const int* __restrict__ rows, const int* __restrict__ cols,
        const float* __restrict__ vals,
        const int* __restrict__ winner, const float* __restrict__ gate,
        const int* __restrict__ rowptr,
        int* __restrict__ ccur, int4* __restrict__ buf) {
    int e = blockIdx.x * blockDim.x + threadIdx.x;
    if (e >= EE) return;
    int r = rows[e];
    float v = vals[e];
    int wn = winner[e];
    float mv = (wn >= 0) ? v * gate[wn] : v;
    int b = r >> 8;
    int pos = rowptr[b << 8] + atomicAdd(&ccur[b], 1);
    buf[pos] = make_int4(r, cols[e], __float_as_int(v), __float_as_int(mv));
}

// pass2: one workgroup per bucket; LDS cursors (row&255 unique within a
// bucket) place each edge at rowptr[row]+lcur++. Reads sequential; writes
// land in the bucket's contiguous ~34KB CSR window -> full-line coalescing.
__global__ __launch_bounds__(256) void scatter_pass2_kernel(
        const int* __restrict__ rowptr, const int4* __restrict__ buf,
        int4* __restrict__ edata) {
    __shared__ int lcur[256];
    const int b = blockIdx.x;
    const int t = threadIdx.x;
    lcur[t] = 0;
    __syncthreads();
    const int beg = rowptr[b << 8];
    const int nxt = (b + 1) << 8;
    const int end = (nxt >= NN) ? EE : rowptr[nxt];
    for (int i = beg + t; i < end; i += 256) {
        int4 ed = buf[i];
        int r = ed.x;
        int pos = rowptr[r] + atomicAdd(&lcur[r & 255], 1);
        edata[pos] = make_int4(ed.y, ed.z, ed.w, 0);
    }
}

// ---------------------------------------------------------------------------
// packed dual-chain gather-SpMM, dwordx4 layout (unchanged from round 1)
// ---------------------------------------------------------------------------
__global__ __launch_bounds__(256) void spmm_packed_kernel(
        const int* __restrict__ rowptr, const int4* __restrict__ edata,
        const unsigned int* __restrict__ zin, unsigned int* __restrict__ zout) {
    int w = (blockIdx.x * blockDim.x + threadIdx.x) >> 6;
    if (w >= NN) return;
    const int lane = threadIdx.x & 63;
    const int g    = lane >> 4;   // edge slot 0..3
    const int sub  = lane & 15;   // u32 quad within node row
    const int beg = rowptr[w], end = rowptr[w + 1];

    float a[8] = {0.f, 0.f, 0.f, 0.f, 0.f, 0.f, 0.f, 0.f};
    int i = beg;
    for (; i + 8 <= end; i += 8) {
        int4 e0 = edata[i + g];
        int4 e1 = edata[i + 4 + g];
        uint4 p0 = *(const uint4*)(zin + (size_t)e0.x * 64 + sub * 4);
        uint4 p1 = *(const uint4*)(zin + (size_t)e1.x * 64 + sub * 4);
        float w0 = (sub < 8) ? __int_as_float(e0.y) : __int_as_float(e0.z);
        float w1 = (sub < 8) ? __int_as_float(e1.y) : __int_as_float(e1.z);
        a[0] = fmaf(w0, bf_lo(p0.x), a[0]); a[1] = fmaf(w0, bf_hi(p0.x), a[1]);
        a[2] = fmaf(w0, bf_lo(p0.y), a[2]); a[3] = fmaf(w0, bf_hi(p0.y), a[3]);
        a[4] = fmaf(w0, bf_lo(p0.z), a[4]); a[5] = fmaf(w0, bf_hi(p0.z), a[5]);
        a[6] = fmaf(w0, bf_lo(p0.w), a[6]); a[7] = fmaf(w0, bf_hi(p0.w), a[7]);
        a[0] = fmaf(w1, bf_lo(p1.x), a[0]); a[1] = fmaf(w1, bf_hi(p1.x), a[1]);
        a[2] = fmaf(w1, bf_lo(p1.y), a[2]); a[3] = fmaf(w1, bf_hi(p1.y), a[3]);
        a[4] = fmaf(w1, bf_lo(p1.z), a[4]); a[5] = fmaf(w1, bf_hi(p1.z), a[5]);
        a[6] = fmaf(w1, bf_lo(p1.w), a[6]); a[7] = fmaf(w1, bf_hi(p1.w), a[7]);
    }
    for (; i < end; i += 4) {
        int idx = i + g;
        int4 e = edata[(idx < end) ? idx : end - 1];
        float wt = (idx < end) ? ((sub < 8) ? __int_as_float(e.y) : __int_as_float(e.z)) : 0.f;
        uint4 p = *(const uint4*)(zin + (size_t)e.x * 64 + sub * 4);
        a[0] = fmaf(wt, bf_lo(p.x), a[0]); a[1] = fmaf(wt, bf_hi(p.x), a[1]);
        a[2] = fmaf(wt, bf_lo(p.y), a[2]); a[3] = fmaf(wt, bf_hi(p.y), a[3]);
        a[4] = fmaf(wt, bf_lo(p.z), a[4]); a[5] = fmaf(wt, bf_hi(p.z), a[5]);
        a[6] = fmaf(wt, bf_lo(p.w), a[6]); a[7] = fmaf(wt, bf_hi(p.w), a[7]);
    }
#pragma unroll
    for (int j = 0; j < 8; ++j) {
        a[j] += __shfl_xor(a[j], 16);
        a[j] += __shfl_xor(a[j], 32);
    }
    if (lane < 16) {
        uint4 o;
        o.x = pack_bf16(a[0], a[1]);
        o.y = pack_bf16(a[2], a[3]);
        o.z = pack_bf16(a[4], a[5]);
        o.w = pack_bf16(a[6], a[7]);
        *(uint4*)(zout + (size_t)w * 64 + sub * 4) = o;
    }
}

// ---------------------------------------------------------------------------
// fold: out = (ego + l1 + l2 + l3) / 4, split x->outx, y->outy
// ---------------------------------------------------------------------------
__global__ void fold_kernel(const float* __restrict__ user, const float* __restrict__ item,
                            const unsigned int* __restrict__ z1,
                            const unsigned int* __restrict__ z2,
                            const unsigned int* __restrict__ z3,
                            float* __restrict__ outx, float* __restrict__ outy) {
    int j = blockIdx.x * blockDim.x + threadIdx.x;
    if (j >= NN * DD) return;
    int n = j >> 6, d = j & 63, dp = d & 31;
    const float* ego = (n < NUM_USERS) ? user + (size_t)n * 64
                                       : item + (size_t)(n - NUM_USERS) * 64;
    float2 e = *(const float2*)(ego + 2 * dp);
    unsigned int u1 = z1[j], u2 = z2[j], u3 = z3[j];
    float s0 = e.x + bf_lo(u1) + bf_lo(u2) + bf_lo(u3);
    float s1 = e.y + bf_hi(u1) + bf_hi(u2) + bf_hi(u3);
    float* dst = ((d < 32) ? outx : outy) + (size_t)n * 64 + 2 * dp;
    *(float2*)dst = make_float2(s0 * 0.25f, s1 * 0.25f);
}

__global__ void final_kernel(const double* __restrict__ gate_sum, float* __restrict__ out_scalar) {
    if (threadIdx.x == 0) out_scalar[0] = (float)(*gate_sum * (1.0 / (double)SS));
}

extern "C" void kernel_launch(void* const* d_in, const int* in_sizes, int n_in,
                              void* d_out, int out_size, void* d_ws, size_t ws_size,
                              hipStream_t stream) {
    const float* user = (const float*)d_in[0];
    const float* item = (const float*)d_in[1];
    const int*   rows = (const int*)d_in[2];
    const int*   cols = (const int*)d_in[3];
    const float* vals = (const float*)d_in[4];
    const int*   sidx = (const int*)d_in[5];
    const float* eps  = (const float*)d_in[6];
    const float* W1   = (const float*)d_in[7];
    const float* b1   = (const float*)d_in[8];
    const float* W2   = (const float*)d_in[9];
    const float* b2   = (const float*)d_in[10];

    float* out  = (float*)d_out;
    const size_t ND = (size_t)NN * DD;
    float* outx = out;
    float* outy = out + ND;
    float* out_scalar = out + 2 * ND;

    unsigned int* wsu = (unsigned int*)d_ws;
    unsigned int* z0 = wsu;
    unsigned int* z1 = wsu + ND;
    unsigned int* z2 = wsu + 2 * ND;
    int4* edata = (int4*)(wsu + 3 * ND);
    // ego16 (19.2 MB) aliases edata (20 MB): live init->gate; edata written
    // only later by scatter pass2 (after gate completes, same stream).
    _Float16* ego16 = (_Float16*)edata;
    // buf (20 MB) aliases z1 (38.4 MB): live pass1->pass2; z1 first written
    // by spmm #1, after pass2 completes.
    int4* buf = (int4*)z1;
    unsigned int* regionA = wsu + 3 * ND + (size_t)EE * 4;
    int*   rowptr = (int*)regionA;                    // 150016 ints (NN+1 used)
    int*   ccur   = (int*)regionA + 150016;           // 586 bucket cursors (doubles as deg)
    float* gate   = (float*)(regionA + 300032);       // SS floats; must outlive pass1
    int*   winner = (int*)(regionA + 700032);         // EE ints
    int*   bsum   = winner + EE;
    double* gate_sum = (double*)(((uintptr_t)(bsum + NB_SCAN) + 7) & ~(uintptr_t)7);

    const int B = 256;
    const int grid_ND = (int)((ND + B - 1) / B);
    const int grid_E  = (EE + B - 1) / B;
    const int grid_spmm = (int)((NN * 64 + B - 1) / B);

    init_kernel<<<grid_ND, B, 0, stream>>>(user, item, z0, ego16, winner, ccur, gate_sum);
    gate_kernel<<<2048, B, 0, stream>>>(ego16, rows, cols, sidx, eps,
                                        W1, b1, W2, b2, gate, gate_sum);
    whist_kernel<<<grid_E, B, 0, stream>>>(rows, sidx, ccur, winner);
    scan1_kernel<<<NB_SCAN, 256, 0, stream>>>(ccur, rowptr, bsum);
    scan2_kernel<<<1, 1024, 0, stream>>>(bsum);
    scan3_kernel<<<grid_ND, B, 0, stream>>>(rowptr, bsum, ccur);
    scatter_pass1_kernel<<<grid_E, B, 0, stream>>>(rows, cols, vals, winner, gate,
                                                   rowptr, ccur, buf);
    scatter_pass2_kernel<<<NBUCKET, 256, 0, stream>>>(rowptr, buf, edata);

    spmm_packed_kernel<<<grid_spmm, B, 0, stream>>>(rowptr, edata, z0, z1);
    spmm_packed_kernel<<<grid_spmm, B, 0, stream>>>(rowptr, edata, z1, z2);
    spmm_packed_kernel<<<grid_spmm, B, 0, stream>>>(rowptr, edata, z2, z0);

    fold_kernel<<<grid_ND, B, 0, stream>>>(user, item, z1, z2, z0, outx, outy);
    final_kernel<<<1, 64, 0, stream>>>(gate_sum, out_scalar);
}

// Round 3
// 509.055 us; speedup vs baseline: 1.6820x; 1.6820x over previous
//
#include <hip/hip_runtime.h>
#include <math.h>

#define NUM_USERS 100000
#define NUM_ITEMS 50000
#define NN 150000
#define DD 64
#define EE 1250000
#define SS 400000
#define TAU 0.2f
#define EDGE_BIAS 0.5f

#define NBUCKET 586     // coarse buckets (row >> 8)
#define NB1 153         // partition blocks
#define TILE 8192       // edges per partition block (153*8192 >= EE)
#define GN (NBUCKET * NB1)        // 89658 ghist entries
#define GB ((GN + 255) / 256)     // 351 scan blocks

typedef __attribute__((ext_vector_type(8))) _Float16 f16x8;
typedef __attribute__((ext_vector_type(2))) _Float16 f16x2;
typedef __attribute__((ext_vector_type(4))) float f32x4;

#define LDW 136  // f16 LDS row stride for gate kernel

// bf16 helpers (RNE, finite inputs)
__device__ __forceinline__ unsigned int pack_bf16(float lo, float hi) {
    unsigned int a = __float_as_uint(lo), b = __float_as_uint(hi);
    a += 0x7fffu + ((a >> 16) & 1u);
    b += 0x7fffu + ((b >> 16) & 1u);
    return (a >> 16) | (b & 0xffff0000u);
}
__device__ __forceinline__ float bf_lo(unsigned int u) { return __uint_as_float(u << 16); }
__device__ __forceinline__ float bf_hi(unsigned int u) { return __uint_as_float(u & 0xffff0000u); }

// ---------------------------------------------------------------------------
// init: z0 bf16 pairs, f16 ego copy for gate gather, winner=-1,
// rowptr[NN]=EE, gate_sum=0.
// ---------------------------------------------------------------------------
__global__ void init_kernel(const float* __restrict__ user, const float* __restrict__ item,
                            unsigned int* __restrict__ z0, _Float16* __restrict__ ego16,
                            int* __restrict__ winner, int* __restrict__ rowptr,
                            double* __restrict__ gate_sum) {
    int j = blockIdx.x * blockDim.x + threadIdx.x;
    if (j < NN * DD) {
        int n = j >> 6, d = j & 63, dp = d & 31;
        const float* ego = (n < NUM_USERS) ? user + (size_t)n * 64
                                           : item + (size_t)(n - NUM_USERS) * 64;
        float2 e = *(const float2*)(ego + 2 * dp);
        z0[j] = pack_bf16(e.x, e.y);
        if (d < 32) {
            f16x2 h;
            h[0] = (_Float16)e.x;
            h[1] = (_Float16)e.y;
            *(f16x2*)(ego16 + (size_t)n * 64 + 2 * dp) = h;
        }
    }
    if (j < EE) winner[j] = -1;
    if (j == 0) { rowptr[NN] = EE; *gate_sum = 0.0; }
}

// ---------------------------------------------------------------------------
// gate MLP via f16 MFMA (unchanged from round 1)
// ---------------------------------------------------------------------------
__global__ __launch_bounds__(256) void gate_kernel(
        const _Float16* __restrict__ ego16,
        const int* __restrict__ rows, const int* __restrict__ cols,
        const int* __restrict__ sidx, const float* __restrict__ eps,
        const float* __restrict__ W1, const float* __restrict__ b1,
        const float* __restrict__ W2, const float* __restrict__ b2,
        float* __restrict__ gate, double* __restrict__ gate_sum) {
    __shared__ _Float16 sh[64 * LDW];
    __shared__ double sdq[4];

    const int t    = threadIdx.x;
    const int lane = t & 63;
    const int w    = t >> 6;
    const int col  = lane & 15;
    const int quad = lane >> 4;

    for (int idx = t; idx < 8192; idx += 256) {
        int k = idx >> 6, n = idx & 63;
        sh[n * LDW + k] = (_Float16)W1[idx];
    }
    float b1v[4];
#pragma unroll
    for (int nt = 0; nt < 4; ++nt) b1v[nt] = b1[nt * 16 + col];
    float w2v[4];
#pragma unroll
    for (int nt = 0; nt < 4; ++nt) w2v[nt] = W2[nt * 16 + col];
    const float b2v = b2[0];
    __syncthreads();

    f16x8 bfrag[4][4];
#pragma unroll
    for (int nt = 0; nt < 4; ++nt)
#pragma unroll
        for (int kk = 0; kk < 4; ++kk)
            bfrag[nt][kk] = *(const f16x8*)&sh[(nt * 16 + col) * LDW + kk * 32 + quad * 8];

    double partial = 0.0;
    const int sloc = t >> 2;
    const int part = t & 3;

    for (int tile = blockIdx.x; tile < SS / 64; tile += gridDim.x) {
        const int s0 = tile * 64;
        __syncthreads();
        {
            const int s = s0 + sloc;
            const int e = sidx[s];
            const int node = (part < 2) ? rows[e] : cols[e];
            const f16x8* s8 = (const f16x8*)(ego16 + (size_t)node * 64 + (part & 1) * 32);
            f16x8* dst = (f16x8*)&sh[sloc * LDW + part * 32];
#pragma unroll
            for (int h = 0; h < 4; ++h) dst[h] = s8[h];
        }
        __syncthreads();

        f32x4 acc[4] = {};
        const _Float16* abase = &sh[(w * 16 + col) * LDW + quad * 8];
#pragma unroll
        for (int kk = 0; kk < 4; ++kk) {
            f16x8 a = *(const f16x8*)(abase + kk * 32);
#pragma unroll
            for (int nt = 0; nt < 4; ++nt)
                acc[nt] = __builtin_amdgcn_mfma_f32_16x16x32_f16(a, bfrag[nt][kk], acc[nt], 0, 0, 0);
        }

        float p[4];
#pragma unroll
        for (int r = 0; r < 4; ++r) {
            float sum = 0.f;
#pragma unroll
            for (int nt = 0; nt < 4; ++nt)
                sum = fmaf(fmaxf(acc[nt][r] + b1v[nt], 0.f), w2v[nt], sum);
#pragma unroll
            for (int off = 8; off >= 1; off >>= 1) sum += __shfl_xor(sum, off);
            p[r] = sum + b2v;
        }
        if (col == 0) {
            const int sb = s0 + w * 16 + quad * 4;
            float4 ev4 = *(const float4*)(eps + sb);
            float g4[4];
            const float evs[4] = {ev4.x, ev4.y, ev4.z, ev4.w};
#pragma unroll
            for (int r = 0; r < 4; ++r) {
                float ev  = evs[r] * (1.f - 2e-6f) + 1e-6f;
                float gum = logf(ev) - log1pf(-ev);
                float z   = (p[r] + gum) * (1.f / TAU);
                float g   = 1.f / (1.f + expf(-z)) + EDGE_BIAS;
                g4[r] = g;
                partial += (double)g;
            }
            *(float4*)(gate + sb) = make_float4(g4[0], g4[1], g4[2], g4[3]);
        }
    }

#pragma unroll
    for (int off = 32; off >= 1; off >>= 1) partial += __shfl_xor(partial, off);
    if (lane == 0) sdq[w] = partial;
    __syncthreads();
    if (t == 0) atomicAdd(gate_sum, sdq[0] + sdq[1] + sdq[2] + sdq[3]);
}

// ---------------------------------------------------------------------------
// Deterministic radix-partition scatter (replaces atomic scatter; lesson from
// round 2: 1.25M global atomics over 586 counters serialize at ~164ns each).
//
// count: per-block LDS histogram over 586 buckets (row>>8); writes
// ghist[bucket*NB1 + blk]. Zero global atomics. Winner atomicMax fused
// (grid-stride; 400K ops over 1.25M addresses = uncontended).
// ---------------------------------------------------------------------------
__global__ __launch_bounds__(256) void bucket_count_kernel(
        const int* __restrict__ rows, const int* __restrict__ sidx,
        int* __restrict__ ghist, int* __restrict__ winner) {
    __shared__ int h[NBUCKET];
    const int t = threadIdx.x;
    for (int i = t; i < NBUCKET; i += 256) h[i] = 0;
    __syncthreads();
    const int base = blockIdx.x * TILE;
    const int end = (base + TILE < EE) ? base + TILE : EE;
    for (int i = base + t; i < end; i += 256) atomicAdd(&h[rows[i] >> 8], 1);
    const int gt = blockIdx.x * 256 + t;
    for (int s = gt; s < SS; s += NB1 * 256) atomicMax(&winner[sidx[s]], s);
    __syncthreads();
    for (int i = t; i < NBUCKET; i += 256) ghist[i * NB1 + blockIdx.x] = h[i];
}

// generic 3-kernel exclusive scan over N ints (in-place), N <= 256*1024
__global__ void gscan1_kernel(int* __restrict__ data, int* __restrict__ bsum, int N) {
    __shared__ int sh[256];
    int tid = threadIdx.x;
    int i = blockIdx.x * 256 + tid;
    int v = (i < N) ? data[i] : 0;
    sh[tid] = v;
    __syncthreads();
    for (int off = 1; off < 256; off <<= 1) {
        int tv = (tid >= off) ? sh[tid - off] : 0;
        __syncthreads();
        sh[tid] += tv;
        __syncthreads();
    }
    if (i < N) data[i] = sh[tid] - v;
    if (tid == 255) bsum[blockIdx.x] = sh[255];
}

__global__ void gscan2_kernel(int* __restrict__ bsum, int NB) {
    __shared__ int sh[1024];
    int tid = threadIdx.x;
    int v = (tid < NB) ? bsum[tid] : 0;
    sh[tid] = v;
    __syncthreads();
    for (int off = 1; off < 1024; off <<= 1) {
        int tv = (tid >= off) ? sh[tid - off] : 0;
        __syncthreads();
        sh[tid] += tv;
        __syncthreads();
    }
    if (tid < NB) bsum[tid] = sh[tid] - v;
}

__global__ void gscan3_kernel(int* __restrict__ data, const int* __restrict__ bsum, int N) {
    int i = blockIdx.x * blockDim.x + threadIdx.x;
    if (i < N) data[i] += bsum[i >> 8];
}

// scatter: each block's writes to a bucket form a contiguous PRIVATE run
// (avg 14 edges = 224B) at base ghist[bucket*NB1+blk]; LDS cursors only.
// mval computed inline.
__global__ __launch_bounds__(256) void bucket_scatter_kernel(
        const int* __restrict__ rows, const int* __restrict__ cols,
        const float* __restrict__ vals,
        const int* __restrict__ winner, const float* __restrict__ gate,
        const int* __restrict__ ghist, int4* __restrict__ buf) {
    __shared__ int sbase[NBUCKET];
    const int t = threadIdx.x;
    for (int i = t; i < NBUCKET; i += 256) sbase[i] = ghist[i * NB1 + blockIdx.x];
    __syncthreads();
    const int base = blockIdx.x * TILE;
    const int end = (base + TILE < EE) ? base + TILE : EE;
    for (int e = base + t; e < end; e += 256) {
        int r = rows[e];
        float v = vals[e];
        int wn = winner[e];
        float mv = (wn >= 0) ? v * gate[wn] : v;
        int pos = atomicAdd(&sbase[r >> 8], 1);
        buf[pos] = make_int4(r, cols[e], __float_as_int(v), __float_as_int(mv));
    }
}

// bucket -> CSR: one block owns one bucket's contiguous window (~34KB, stays
// in its XCD's L2 -> full-line writes). Builds per-row counts in LDS, scans
// them to derive rowptr for its 256 rows (eliminates the old 1.25M-atomic
// degree histogram + 150K row scan), then places edges.
__global__ __launch_bounds__(256) void bucket_to_csr_kernel(
        const int* __restrict__ ghist, const int4* __restrict__ buf,
        int* __restrict__ rowptr, int4* __restrict__ edata) {
    __shared__ int sh[256];
    const int b = blockIdx.x;
    const int t = threadIdx.x;
    const int rbeg = ghist[b * NB1];
    const int rend = (b + 1 < NBUCKET) ? ghist[(b + 1) * NB1] : EE;
    sh[t] = 0;
    __syncthreads();
    for (int i = rbeg + t; i < rend; i += 256) atomicAdd(&sh[buf[i].x & 255], 1);
    __syncthreads();
    int cnt = sh[t];
    for (int off = 1; off < 256; off <<= 1) {
        int tv = (t >= off) ? sh[t - off] : 0;
        __syncthreads();
        sh[t] += tv;
        __syncthreads();
    }
    int rowbase = rbeg + sh[t] - cnt;   // exclusive scan -> row start
    int r = (b << 8) + t;
    if (r < NN) rowptr[r] = rowbase;
    __syncthreads();
    sh[t] = rowbase;                    // reuse as per-row cursor
    __syncthreads();
    for (int i = rbeg + t; i < rend; i += 256) {
        int4 ed = buf[i];
        int pos = atomicAdd(&sh[ed.x & 255], 1);
        edata[pos] = make_int4(ed.y, ed.z, ed.w, 0);
    }
}

// ---------------------------------------------------------------------------
// packed dual-chain gather-SpMM, dwordx4 layout (unchanged)
// ---------------------------------------------------------------------------
__global__ __launch_bounds__(256) void spmm_packed_kernel(
        const int* __restrict__ rowptr, const int4* __restrict__ edata,
        const unsigned int* __restrict__ zin, unsigned int* __restrict__ zout) {
    int w = (blockIdx.x * blockDim.x + threadIdx.x) >> 6;
    if (w >= NN) return;
    const int lane = threadIdx.x & 63;
    const int g    = lane >> 4;   // edge slot 0..3
    const int sub  = lane & 15;   // u32 quad within node row
    const int beg = rowptr[w], end = rowptr[w + 1];

    float a[8] = {0.f, 0.f, 0.f, 0.f, 0.f, 0.f, 0.f, 0.f};
    int i = beg;
    for (; i + 8 <= end; i += 8) {
        int4 e0 = edata[i + g];
        int4 e1 = edata[i + 4 + g];
        uint4 p0 = *(const uint4*)(zin + (size_t)e0.x * 64 + sub * 4);
        uint4 p1 = *(const uint4*)(zin + (size_t)e1.x * 64 + sub * 4);
        float w0 = (sub < 8) ? __int_as_float(e0.y) : __int_as_float(e0.z);
        float w1 = (sub < 8) ? __int_as_float(e1.y) : __int_as_float(e1.z);
        a[0] = fmaf(w0, bf_lo(p0.x), a[0]); a[1] = fmaf(w0, bf_hi(p0.x), a[1]);
        a[2] = fmaf(w0, bf_lo(p0.y), a[2]); a[3] = fmaf(w0, bf_hi(p0.y), a[3]);
        a[4] = fmaf(w0, bf_lo(p0.z), a[4]); a[5] = fmaf(w0, bf_hi(p0.z), a[5]);
        a[6] = fmaf(w0, bf_lo(p0.w), a[6]); a[7] = fmaf(w0, bf_hi(p0.w), a[7]);
        a[0] = fmaf(w1, bf_lo(p1.x), a[0]); a[1] = fmaf(w1, bf_hi(p1.x), a[1]);
        a[2] = fmaf(w1, bf_lo(p1.y), a[2]); a[3] = fmaf(w1, bf_hi(p1.y), a[3]);
        a[4] = fmaf(w1, bf_lo(p1.z), a[4]); a[5] = fmaf(w1, bf_hi(p1.z), a[5]);
        a[6] = fmaf(w1, bf_lo(p1.w), a[6]); a[7] = fmaf(w1, bf_hi(p1.w), a[7]);
    }
    for (; i < end; i += 4) {
        int idx = i + g;
        int4 e = edata[(idx < end) ? idx : end - 1];
        float wt = (idx < end) ? ((sub < 8) ? __int_as_float(e.y) : __int_as_float(e.z)) : 0.f;
        uint4 p = *(const uint4*)(zin + (size_t)e.x * 64 + sub * 4);
        a[0] = fmaf(wt, bf_lo(p.x), a[0]); a[1] = fmaf(wt, bf_hi(p.x), a[1]);
        a[2] = fmaf(wt, bf_lo(p.y), a[2]); a[3] = fmaf(wt, bf_hi(p.y), a[3]);
        a[4] = fmaf(wt, bf_lo(p.z), a[4]); a[5] = fmaf(wt, bf_hi(p.z), a[5]);
        a[6] = fmaf(wt, bf_lo(p.w), a[6]); a[7] = fmaf(wt, bf_hi(p.w), a[7]);
    }
#pragma unroll
    for (int j = 0; j < 8; ++j) {
        a[j] += __shfl_xor(a[j], 16);
        a[j] += __shfl_xor(a[j], 32);
    }
    if (lane < 16) {
        uint4 o;
        o.x = pack_bf16(a[0], a[1]);
        o.y = pack_bf16(a[2], a[3]);
        o.z = pack_bf16(a[4], a[5]);
        o.w = pack_bf16(a[6], a[7]);
        *(uint4*)(zout + (size_t)w * 64 + sub * 4) = o;
    }
}

// ---------------------------------------------------------------------------
// fold: out = (ego + l1 + l2 + l3) / 4, split x->outx, y->outy
// ---------------------------------------------------------------------------
__global__ void fold_kernel(const float* __restrict__ user, const float* __restrict__ item,
                            const unsigned int* __restrict__ z1,
                            const unsigned int* __restrict__ z2,
                            const unsigned int* __restrict__ z3,
                            float* __restrict__ outx, float* __restrict__ outy) {
    int j = blockIdx.x * blockDim.x + threadIdx.x;
    if (j >= NN * DD) return;
    int n = j >> 6, d = j & 63, dp = d & 31;
    const float* ego = (n < NUM_USERS) ? user + (size_t)n * 64
                                       : item + (size_t)(n - NUM_USERS) * 64;
    float2 e = *(const float2*)(ego + 2 * dp);
    unsigned int u1 = z1[j], u2 = z2[j], u3 = z3[j];
    float s0 = e.x + bf_lo(u1) + bf_lo(u2) + bf_lo(u3);
    float s1 = e.y + bf_hi(u1) + bf_hi(u2) + bf_hi(u3);
    float* dst = ((d < 32) ? outx : outy) + (size_t)n * 64 + 2 * dp;
    *(float2*)dst = make_float2(s0 * 0.25f, s1 * 0.25f);
}

__global__ void final_kernel(const double* __restrict__ gate_sum, float* __restrict__ out_scalar) {
    if (threadIdx.x == 0) out_scalar[0] = (float)(*gate_sum * (1.0 / (double)SS));
}

extern "C" void kernel_launch(void* const* d_in, const int* in_sizes, int n_in,
                              void* d_out, int out_size, void* d_ws, size_t ws_size,
                              hipStream_t stream) {
    const float* user = (const float*)d_in[0];
    const float* item = (const float*)d_in[1];
    const int*   rows = (const int*)d_in[2];
    const int*   cols = (const int*)d_in[3];
    const float* vals = (const float*)d_in[4];
    const int*   sidx = (const int*)d_in[5];
    const float* eps  = (const float*)d_in[6];
    const float* W1   = (const float*)d_in[7];
    const float* b1   = (const float*)d_in[8];
    const float* W2   = (const float*)d_in[9];
    const float* b2   = (const float*)d_in[10];

    float* out  = (float*)d_out;
    const size_t ND = (size_t)NN * DD;
    float* outx = out;
    float* outy = out + ND;
    float* out_scalar = out + 2 * ND;

    unsigned int* wsu = (unsigned int*)d_ws;
    unsigned int* z0 = wsu;
    unsigned int* z1 = wsu + ND;
    unsigned int* z2 = wsu + 2 * ND;
    int4* edata = (int4*)(wsu + 3 * ND);
    // ego16 (19.2 MB) aliases edata (20 MB): live init->gate; edata written
    // only by bucket_to_csr (after gate completes, same stream).
    _Float16* ego16 = (_Float16*)edata;
    // buf (20 MB) aliases z1 (38.4 MB): live scatter->to_csr; z1 first
    // written by spmm #1, after to_csr completes.
    int4* buf = (int4*)z1;
    unsigned int* regionA = wsu + 3 * ND + (size_t)EE * 4;
    int*   rowptr = (int*)regionA;                    // [0, 150016)
    float* gate   = (float*)(regionA + 150016);       // SS floats
    int*   ghist  = (int*)(regionA + 550016);         // GN = 89658 ints
    int*   bsum2  = (int*)(regionA + 639680);         // GB = 351 ints
    int*   winner = (int*)(regionA + 640032);         // EE ints
    double* gate_sum = (double*)(((uintptr_t)(regionA + 640032 + EE) + 7) & ~(uintptr_t)7);

    const int B = 256;
    const int grid_ND = (int)((ND + B - 1) / B);
    const int grid_spmm = (int)((NN * 64 + B - 1) / B);

    init_kernel<<<grid_ND, B, 0, stream>>>(user, item, z0, ego16, winner, rowptr, gate_sum);
    gate_kernel<<<2048, B, 0, stream>>>(ego16, rows, cols, sidx, eps,
                                        W1, b1, W2, b2, gate, gate_sum);
    bucket_count_kernel<<<NB1, B, 0, stream>>>(rows, sidx, ghist, winner);
    gscan1_kernel<<<GB, 256, 0, stream>>>(ghist, bsum2, GN);
    gscan2_kernel<<<1, 1024, 0, stream>>>(bsum2, GB);
    gscan3_kernel<<<GB, 256, 0, stream>>>(ghist, bsum2, GN);
    bucket_scatter_kernel<<<NB1, B, 0, stream>>>(rows, cols, vals, winner, gate, ghist, buf);
    bucket_to_csr_kernel<<<NBUCKET, B, 0, stream>>>(ghist, buf, rowptr, edata);

    spmm_packed_kernel<<<grid_spmm, B, 0, stream>>>(rowptr, edata, z0, z1);
    spmm_packed_kernel<<<grid_spmm, B, 0, stream>>>(rowptr, edata, z1, z2);
    spmm_packed_kernel<<<grid_spmm, B, 0, stream>>>(rowptr, edata, z2, z0);

    fold_kernel<<<grid_ND, B, 0, stream>>>(user, item, z1, z2, z0, outx, outy);
    final_kernel<<<1, 64, 0, stream>>>(gate_sum, out_scalar);
}

// Round 4
// 503.312 us; speedup vs baseline: 1.7012x; 1.0114x over previous
//
#include <hip/hip_runtime.h>
#include <math.h>

#define NUM_USERS 100000
#define NUM_ITEMS 50000
#define NN 150000
#define DD 64
#define EE 1250000
#define SS 400000
#define TAU 0.2f
#define EDGE_BIAS 0.5f

#define NBUCKET 586     // coarse buckets (row >> 8)
#define NB1 153         // partition blocks
#define TILE 8192       // edges per partition block (153*8192 >= EE)
#define GN (NBUCKET * NB1)        // 89658 ghist entries
#define GB ((GN + 255) / 256)     // 351 scan blocks

typedef __attribute__((ext_vector_type(8))) _Float16 f16x8;
typedef __attribute__((ext_vector_type(2))) _Float16 f16x2;
typedef __attribute__((ext_vector_type(4))) float f32x4;

#define LDW 136  // f16 LDS row stride for gate W1 prologue

// bf16 helpers (RNE, finite inputs)
__device__ __forceinline__ unsigned int pack_bf16(float lo, float hi) {
    unsigned int a = __float_as_uint(lo), b = __float_as_uint(hi);
    a += 0x7fffu + ((a >> 16) & 1u);
    b += 0x7fffu + ((b >> 16) & 1u);
    return (a >> 16) | (b & 0xffff0000u);
}
__device__ __forceinline__ float bf_lo(unsigned int u) { return __uint_as_float(u << 16); }
__device__ __forceinline__ float bf_hi(unsigned int u) { return __uint_as_float(u & 0xffff0000u); }

// ---------------------------------------------------------------------------
// init: z0 bf16 pairs, f16 ego copy for gate gather, winner=-1,
// rowptr[NN]=EE, gate_sum=0.
// ---------------------------------------------------------------------------
__global__ void init_kernel(const float* __restrict__ user, const float* __restrict__ item,
                            unsigned int* __restrict__ z0, _Float16* __restrict__ ego16,
                            int* __restrict__ winner, int* __restrict__ rowptr,
                            double* __restrict__ gate_sum) {
    int j = blockIdx.x * blockDim.x + threadIdx.x;
    if (j < NN * DD) {
        int n = j >> 6, d = j & 63, dp = d & 31;
        const float* ego = (n < NUM_USERS) ? user + (size_t)n * 64
                                           : item + (size_t)(n - NUM_USERS) * 64;
        float2 e = *(const float2*)(ego + 2 * dp);
        z0[j] = pack_bf16(e.x, e.y);
        if (d < 32) {
            f16x2 h;
            h[0] = (_Float16)e.x;
            h[1] = (_Float16)e.y;
            *(f16x2*)(ego16 + (size_t)n * 64 + 2 * dp) = h;
        }
    }
    if (j < EE) winner[j] = -1;
    if (j == 0) { rowptr[NN] = EE; *gate_sum = 0.0; }
}

// ---------------------------------------------------------------------------
// gate MLP via f16 MFMA, barrier-free direct-gather version.
// R3 diagnosis: LDS-staged tiles were a barrier-bracketed latency chain
// (67us for ~15us of memory service). The 16x16x32 A-fragment for lane
// (col,quad) at K-step kk is a contiguous 16B slice of one node's ego16
// row -> gather it straight into registers: one wave = 16 edges, 4
// independent gathers/lane, zero loop barriers.
// ---------------------------------------------------------------------------
__global__ __launch_bounds__(256) void gate_kernel(
        const _Float16* __restrict__ ego16,
        const int* __restrict__ rows, const int* __restrict__ cols,
        const int* __restrict__ sidx, const float* __restrict__ eps,
        const float* __restrict__ W1, const float* __restrict__ b1,
        const float* __restrict__ W2, const float* __restrict__ b2,
        float* __restrict__ gate, double* __restrict__ gate_sum) {
    __shared__ _Float16 sh[64 * LDW];
    __shared__ double sdq[4];

    const int t    = threadIdx.x;
    const int lane = t & 63;
    const int w    = t >> 6;
    const int col  = lane & 15;
    const int quad = lane >> 4;

    // prologue: stage W1 transposed, build B-fragments, then LDS is dead
    for (int idx = t; idx < 8192; idx += 256) {
        int k = idx >> 6, n = idx & 63;
        sh[n * LDW + k] = (_Float16)W1[idx];
    }
    float b1v[4];
#pragma unroll
    for (int nt = 0; nt < 4; ++nt) b1v[nt] = b1[nt * 16 + col];
    float w2v[4];
#pragma unroll
    for (int nt = 0; nt < 4; ++nt) w2v[nt] = W2[nt * 16 + col];
    const float b2v = b2[0];
    __syncthreads();

    f16x8 bfrag[4][4];
#pragma unroll
    for (int nt = 0; nt < 4; ++nt)
#pragma unroll
        for (int kk = 0; kk < 4; ++kk)
            bfrag[nt][kk] = *(const f16x8*)&sh[(nt * 16 + col) * LDW + kk * 32 + quad * 8];

    double partial = 0.0;
    const int nwaves = gridDim.x * 4;
    const int wid = blockIdx.x * 4 + w;

    for (int grp = wid; grp < SS / 16; grp += nwaves) {
        const int gbase = grp * 16;
        const int sid = sidx[gbase + col];
        const int su = rows[sid];
        const int sv = cols[sid];
        const _Float16* pu = ego16 + (size_t)su * 64 + quad * 8;
        const _Float16* pv = ego16 + (size_t)sv * 64 + quad * 8;
        // A-fragments straight from global: kk0/1 = su halves, kk2/3 = sv
        f16x8 a0 = *(const f16x8*)(pu);
        f16x8 a1 = *(const f16x8*)(pu + 32);
        f16x8 a2 = *(const f16x8*)(pv);
        f16x8 a3 = *(const f16x8*)(pv + 32);

        f32x4 acc[4] = {};
#pragma unroll
        for (int nt = 0; nt < 4; ++nt) {
            acc[nt] = __builtin_amdgcn_mfma_f32_16x16x32_f16(a0, bfrag[nt][0], acc[nt], 0, 0, 0);
            acc[nt] = __builtin_amdgcn_mfma_f32_16x16x32_f16(a1, bfrag[nt][1], acc[nt], 0, 0, 0);
            acc[nt] = __builtin_amdgcn_mfma_f32_16x16x32_f16(a2, bfrag[nt][2], acc[nt], 0, 0, 0);
            acc[nt] = __builtin_amdgcn_mfma_f32_16x16x32_f16(a3, bfrag[nt][3], acc[nt], 0, 0, 0);
        }

        float p[4];
#pragma unroll
        for (int r = 0; r < 4; ++r) {
            float sum = 0.f;
#pragma unroll
            for (int nt = 0; nt < 4; ++nt)
                sum = fmaf(fmaxf(acc[nt][r] + b1v[nt], 0.f), w2v[nt], sum);
#pragma unroll
            for (int off = 8; off >= 1; off >>= 1) sum += __shfl_xor(sum, off);
            p[r] = sum + b2v;   // edge gbase + quad*4 + r
        }
        if (col == 0) {
            const int sb = gbase + quad * 4;
            float4 ev4 = *(const float4*)(eps + sb);
            float g4[4];
            const float evs[4] = {ev4.x, ev4.y, ev4.z, ev4.w};
#pragma unroll
            for (int r = 0; r < 4; ++r) {
                float ev  = evs[r] * (1.f - 2e-6f) + 1e-6f;
                float gum = logf(ev) - log1pf(-ev);
                float z   = (p[r] + gum) * (1.f / TAU);
                float g   = 1.f / (1.f + expf(-z)) + EDGE_BIAS;
                g4[r] = g;
                partial += (double)g;
            }
            *(float4*)(gate + sb) = make_float4(g4[0], g4[1], g4[2], g4[3]);
        }
    }

#pragma unroll
    for (int off = 32; off >= 1; off >>= 1) partial += __shfl_xor(partial, off);
    if (lane == 0) sdq[w] = partial;
    __syncthreads();
    if (t == 0) atomicAdd(gate_sum, sdq[0] + sdq[1] + sdq[2] + sdq[3]);
}

// ---------------------------------------------------------------------------
// Deterministic radix-partition scatter (unchanged from round 3)
// ---------------------------------------------------------------------------
__global__ __launch_bounds__(256) void bucket_count_kernel(
        const int* __restrict__ rows, const int* __restrict__ sidx,
        int* __restrict__ ghist, int* __restrict__ winner) {
    __shared__ int h[NBUCKET];
    const int t = threadIdx.x;
    for (int i = t; i < NBUCKET; i += 256) h[i] = 0;
    __syncthreads();
    const int base = blockIdx.x * TILE;
    const int end = (base + TILE < EE) ? base + TILE : EE;
    for (int i = base + t; i < end; i += 256) atomicAdd(&h[rows[i] >> 8], 1);
    const int gt = blockIdx.x * 256 + t;
    for (int s = gt; s < SS; s += NB1 * 256) atomicMax(&winner[sidx[s]], s);
    __syncthreads();
    for (int i = t; i < NBUCKET; i += 256) ghist[i * NB1 + blockIdx.x] = h[i];
}

__global__ void gscan1_kernel(int* __restrict__ data, int* __restrict__ bsum, int N) {
    __shared__ int sh[256];
    int tid = threadIdx.x;
    int i = blockIdx.x * 256 + tid;
    int v = (i < N) ? data[i] : 0;
    sh[tid] = v;
    __syncthreads();
    for (int off = 1; off < 256; off <<= 1) {
        int tv = (tid >= off) ? sh[tid - off] : 0;
        __syncthreads();
        sh[tid] += tv;
        __syncthreads();
    }
    if (i < N) data[i] = sh[tid] - v;
    if (tid == 255) bsum[blockIdx.x] = sh[255];
}

__global__ void gscan2_kernel(int* __restrict__ bsum, int NB) {
    __shared__ int sh[1024];
    int tid = threadIdx.x;
    int v = (tid < NB) ? bsum[tid] : 0;
    sh[tid] = v;
    __syncthreads();
    for (int off = 1; off < 1024; off <<= 1) {
        int tv = (tid >= off) ? sh[tid - off] : 0;
        __syncthreads();
        sh[tid] += tv;
        __syncthreads();
    }
    if (tid < NB) bsum[tid] = sh[tid] - v;
}

__global__ void gscan3_kernel(int* __restrict__ data, const int* __restrict__ bsum, int N) {
    int i = blockIdx.x * blockDim.x + threadIdx.x;
    if (i < N) data[i] += bsum[i >> 8];
}

__global__ __launch_bounds__(256) void bucket_scatter_kernel(
        const int* __restrict__ rows, const int* __restrict__ cols,
        const float* __restrict__ vals,
        const int* __restrict__ winner, const float* __restrict__ gate,
        const int* __restrict__ ghist, int4* __restrict__ buf) {
    __shared__ int sbase[NBUCKET];
    const int t = threadIdx.x;
    for (int i = t; i < NBUCKET; i += 256) sbase[i] = ghist[i * NB1 + blockIdx.x];
    __syncthreads();
    const int base = blockIdx.x * TILE;
    const int end = (base + TILE < EE) ? base + TILE : EE;
    for (int e = base + t; e < end; e += 256) {
        int r = rows[e];
        float v = vals[e];
        int wn = winner[e];
        float mv = (wn >= 0) ? v * gate[wn] : v;
        int pos = atomicAdd(&sbase[r >> 8], 1);
        buf[pos] = make_int4(r, cols[e], __float_as_int(v), __float_as_int(mv));
    }
}

__global__ __launch_bounds__(256) void bucket_to_csr_kernel(
        const int* __restrict__ ghist, const int4* __restrict__ buf,
        int* __restrict__ rowptr, int4* __restrict__ edata) {
    __shared__ int sh[256];
    const int b = blockIdx.x;
    const int t = threadIdx.x;
    const int rbeg = ghist[b * NB1];
    const int rend = (b + 1 < NBUCKET) ? ghist[(b + 1) * NB1] : EE;
    sh[t] = 0;
    __syncthreads();
    for (int i = rbeg + t; i < rend; i += 256) atomicAdd(&sh[buf[i].x & 255], 1);
    __syncthreads();
    int cnt = sh[t];
    for (int off = 1; off < 256; off <<= 1) {
        int tv = (t >= off) ? sh[t - off] : 0;
        __syncthreads();
        sh[t] += tv;
        __syncthreads();
    }
    int rowbase = rbeg + sh[t] - cnt;
    int r = (b << 8) + t;
    if (r < NN) rowptr[r] = rowbase;
    __syncthreads();
    sh[t] = rowbase;
    __syncthreads();
    for (int i = rbeg + t; i < rend; i += 256) {
        int4 ed = buf[i];
        int pos = atomicAdd(&sh[ed.x & 255], 1);
        edata[pos] = make_int4(ed.y, ed.z, ed.w, 0);
    }
}

// ---------------------------------------------------------------------------
// packed dual-chain gather-SpMM, dwordx4 layout (unchanged)
// ---------------------------------------------------------------------------
__global__ __launch_bounds__(256) void spmm_packed_kernel(
        const int* __restrict__ rowptr, const int4* __restrict__ edata,
        const unsigned int* __restrict__ zin, unsigned int* __restrict__ zout) {
    int w = (blockIdx.x * blockDim.x + threadIdx.x) >> 6;
    if (w >= NN) return;
    const int lane = threadIdx.x & 63;
    const int g    = lane >> 4;
    const int sub  = lane & 15;
    const int beg = rowptr[w], end = rowptr[w + 1];

    float a[8] = {0.f, 0.f, 0.f, 0.f, 0.f, 0.f, 0.f, 0.f};
    int i = beg;
    for (; i + 8 <= end; i += 8) {
        int4 e0 = edata[i + g];
        int4 e1 = edata[i + 4 + g];
        uint4 p0 = *(const uint4*)(zin + (size_t)e0.x * 64 + sub * 4);
        uint4 p1 = *(const uint4*)(zin + (size_t)e1.x * 64 + sub * 4);
        float w0 = (sub < 8) ? __int_as_float(e0.y) : __int_as_float(e0.z);
        float w1 = (sub < 8) ? __int_as_float(e1.y) : __int_as_float(e1.z);
        a[0] = fmaf(w0, bf_lo(p0.x), a[0]); a[1] = fmaf(w0, bf_hi(p0.x), a[1]);
        a[2] = fmaf(w0, bf_lo(p0.y), a[2]); a[3] = fmaf(w0, bf_hi(p0.y), a[3]);
        a[4] = fmaf(w0, bf_lo(p0.z), a[4]); a[5] = fmaf(w0, bf_hi(p0.z), a[5]);
        a[6] = fmaf(w0, bf_lo(p0.w), a[6]); a[7] = fmaf(w0, bf_hi(p0.w), a[7]);
        a[0] = fmaf(w1, bf_lo(p1.x), a[0]); a[1] = fmaf(w1, bf_hi(p1.x), a[1]);
        a[2] = fmaf(w1, bf_lo(p1.y), a[2]); a[3] = fmaf(w1, bf_hi(p1.y), a[3]);
        a[4] = fmaf(w1, bf_lo(p1.z), a[4]); a[5] = fmaf(w1, bf_hi(p1.z), a[5]);
        a[6] = fmaf(w1, bf_lo(p1.w), a[6]); a[7] = fmaf(w1, bf_hi(p1.w), a[7]);
    }
    for (; i < end; i += 4) {
        int idx = i + g;
        int4 e = edata[(idx < end) ? idx : end - 1];
        float wt = (idx < end) ? ((sub < 8) ? __int_as_float(e.y) : __int_as_float(e.z)) : 0.f;
        uint4 p = *(const uint4*)(zin + (size_t)e.x * 64 + sub * 4);
        a[0] = fmaf(wt, bf_lo(p.x), a[0]); a[1] = fmaf(wt, bf_hi(p.x), a[1]);
        a[2] = fmaf(wt, bf_lo(p.y), a[2]); a[3] = fmaf(wt, bf_hi(p.y), a[3]);
        a[4] = fmaf(wt, bf_lo(p.z), a[4]); a[5] = fmaf(wt, bf_hi(p.z), a[5]);
        a[6] = fmaf(wt, bf_lo(p.w), a[6]); a[7] = fmaf(wt, bf_hi(p.w), a[7]);
    }
#pragma unroll
    for (int j = 0; j < 8; ++j) {
        a[j] += __shfl_xor(a[j], 16);
        a[j] += __shfl_xor(a[j], 32);
    }
    if (lane < 16) {
        uint4 o;
        o.x = pack_bf16(a[0], a[1]);
        o.y = pack_bf16(a[2], a[3]);
        o.z = pack_bf16(a[4], a[5]);
        o.w = pack_bf16(a[6], a[7]);
        *(uint4*)(zout + (size_t)w * 64 + sub * 4) = o;
    }
}

// ---------------------------------------------------------------------------
// final SpMM layer fused with fold: computes z3 row in registers (f32,
// unrounded) then reads z1/z2/ego rows sequentially and writes the mean
// outputs directly. Eliminates the separate fold pass (-77MB traffic).
// ---------------------------------------------------------------------------
__global__ __launch_bounds__(256) void spmm_final_kernel(
        const int* __restrict__ rowptr, const int4* __restrict__ edata,
        const unsigned int* __restrict__ zin,
        const unsigned int* __restrict__ z1, const unsigned int* __restrict__ z2,
        const float* __restrict__ user, const float* __restrict__ item,
        float* __restrict__ outx, float* __restrict__ outy) {
    int w = (blockIdx.x * blockDim.x + threadIdx.x) >> 6;
    if (w >= NN) return;
    const int lane = threadIdx.x & 63;
    const int g    = lane >> 4;
    const int sub  = lane & 15;
    const int beg = rowptr[w], end = rowptr[w + 1];

    float a[8] = {0.f, 0.f, 0.f, 0.f, 0.f, 0.f, 0.f, 0.f};
    int i = beg;
    for (; i + 8 <= end; i += 8) {
        int4 e0 = edata[i + g];
        int4 e1 = edata[i + 4 + g];
        uint4 p0 = *(const uint4*)(zin + (size_t)e0.x * 64 + sub * 4);
        uint4 p1 = *(const uint4*)(zin + (size_t)e1.x * 64 + sub * 4);
        float w0 = (sub < 8) ? __int_as_float(e0.y) : __int_as_float(e0.z);
        float w1 = (sub < 8) ? __int_as_float(e1.y) : __int_as_float(e1.z);
        a[0] = fmaf(w0, bf_lo(p0.x), a[0]); a[1] = fmaf(w0, bf_hi(p0.x), a[1]);
        a[2] = fmaf(w0, bf_lo(p0.y), a[2]); a[3] = fmaf(w0, bf_hi(p0.y), a[3]);
        a[4] = fmaf(w0, bf_lo(p0.z), a[4]); a[5] = fmaf(w0, bf_hi(p0.z), a[5]);
        a[6] = fmaf(w0, bf_lo(p0.w), a[6]); a[7] = fmaf(w0, bf_hi(p0.w), a[7]);
        a[0] = fmaf(w1, bf_lo(p1.x), a[0]); a[1] = fmaf(w1, bf_hi(p1.x), a[1]);
        a[2] = fmaf(w1, bf_lo(p1.y), a[2]); a[3] = fmaf(w1, bf_hi(p1.y), a[3]);
        a[4] = fmaf(w1, bf_lo(p1.z), a[4]); a[5] = fmaf(w1, bf_hi(p1.z), a[5]);
        a[6] = fmaf(w1, bf_lo(p1.w), a[6]); a[7] = fmaf(w1, bf_hi(p1.w), a[7]);
    }
    for (; i < end; i += 4) {
        int idx = i + g;
        int4 e = edata[(idx < end) ? idx : end - 1];
        float wt = (idx < end) ? ((sub < 8) ? __int_as_float(e.y) : __int_as_float(e.z)) : 0.f;
        uint4 p = *(const uint4*)(zin + (size_t)e.x * 64 + sub * 4);
        a[0] = fmaf(wt, bf_lo(p.x), a[0]); a[1] = fmaf(wt, bf_hi(p.x), a[1]);
        a[2] = fmaf(wt, bf_lo(p.y), a[2]); a[3] = fmaf(wt, bf_hi(p.y), a[3]);
        a[4] = fmaf(wt, bf_lo(p.z), a[4]); a[5] = fmaf(wt, bf_hi(p.z), a[5]);
        a[6] = fmaf(wt, bf_lo(p.w), a[6]); a[7] = fmaf(wt, bf_hi(p.w), a[7]);
    }
#pragma unroll
    for (int j = 0; j < 8; ++j) {
        a[j] += __shfl_xor(a[j], 16);
        a[j] += __shfl_xor(a[j], 32);
    }
    if (lane < 16) {
        // lane sub holds dims [8*(sub&7) .. +8) of chain (sub<8 ? x : y)
        uint4 u1 = *(const uint4*)(z1 + (size_t)w * 64 + sub * 4);
        uint4 u2 = *(const uint4*)(z2 + (size_t)w * 64 + sub * 4);
        const float* eg = (w < NUM_USERS) ? user + (size_t)w * 64
                                          : item + (size_t)(w - NUM_USERS) * 64;
        eg += 8 * (sub & 7);
        float4 e0 = *(const float4*)(eg);
        float4 e1 = *(const float4*)(eg + 4);
        float4 o0, o1;
        o0.x = (e0.x + bf_lo(u1.x) + bf_lo(u2.x) + a[0]) * 0.25f;
        o0.y = (e0.y + bf_hi(u1.x) + bf_hi(u2.x) + a[1]) * 0.25f;
        o0.z = (e0.z + bf_lo(u1.y) + bf_lo(u2.y) + a[2]) * 0.25f;
        o0.w = (e0.w + bf_hi(u1.y) + bf_hi(u2.y) + a[3]) * 0.25f;
        o1.x = (e1.x + bf_lo(u1.z) + bf_lo(u2.z) + a[4]) * 0.25f;
        o1.y = (e1.y + bf_hi(u1.z) + bf_hi(u2.z) + a[5]) * 0.25f;
        o1.z = (e1.z + bf_lo(u1.w) + bf_lo(u2.w) + a[6]) * 0.25f;
        o1.w = (e1.w + bf_hi(u1.w) + bf_hi(u2.w) + a[7]) * 0.25f;
        float* dst = ((sub < 8) ? outx : outy) + (size_t)w * 64 + 8 * (sub & 7);
        *(float4*)dst = o0;
        *(float4*)(dst + 4) = o1;
    }
}

__global__ void final_kernel(const double* __restrict__ gate_sum, float* __restrict__ out_scalar) {
    if (threadIdx.x == 0) out_scalar[0] = (float)(*gate_sum * (1.0 / (double)SS));
}

extern "C" void kernel_launch(void* const* d_in, const int* in_sizes, int n_in,
                              void* d_out, int out_size, void* d_ws, size_t ws_size,
                              hipStream_t stream) {
    const float* user = (const float*)d_in[0];
    const float* item = (const float*)d_in[1];
    const int*   rows = (const int*)d_in[2];
    const int*   cols = (const int*)d_in[3];
    const float* vals = (const float*)d_in[4];
    const int*   sidx = (const int*)d_in[5];
    const float* eps  = (const float*)d_in[6];
    const float* W1   = (const float*)d_in[7];
    const float* b1   = (const float*)d_in[8];
    const float* W2   = (const float*)d_in[9];
    const float* b2   = (const float*)d_in[10];

    float* out  = (float*)d_out;
    const size_t ND = (size_t)NN * DD;
    float* outx = out;
    float* outy = out + ND;
    float* out_scalar = out + 2 * ND;

    unsigned int* wsu = (unsigned int*)d_ws;
    unsigned int* z0 = wsu;
    unsigned int* z1 = wsu + ND;
    unsigned int* z2 = wsu + 2 * ND;
    int4* edata = (int4*)(wsu + 3 * ND);
    // ego16 (19.2 MB) aliases edata (20 MB): live init->gate; edata written
    // only by bucket_to_csr (after gate completes, same stream).
    _Float16* ego16 = (_Float16*)edata;
    // buf (20 MB) aliases z1 (38.4 MB): live scatter->to_csr; z1 first
    // written by spmm #1, after to_csr completes.
    int4* buf = (int4*)z1;
    unsigned int* regionA = wsu + 3 * ND + (size_t)EE * 4;
    int*   rowptr = (int*)regionA;                    // [0, 150016)
    float* gate   = (float*)(regionA + 150016);       // SS floats
    int*   ghist  = (int*)(regionA + 550016);         // GN = 89658 ints
    int*   bsum2  = (int*)(regionA + 639680);         // GB = 351 ints
    int*   winner = (int*)(regionA + 640032);         // EE ints
    double* gate_sum = (double*)(((uintptr_t)(regionA + 640032 + EE) + 7) & ~(uintptr_t)7);

    const int B = 256;
    const int grid_ND = (int)((ND + B - 1) / B);
    const int grid_spmm = (int)((NN * 64 + B - 1) / B);

    init_kernel<<<grid_ND, B, 0, stream>>>(user, item, z0, ego16, winner, rowptr, gate_sum);
    gate_kernel<<<2048, B, 0, stream>>>(ego16, rows, cols, sidx, eps,
                                        W1, b1, W2, b2, gate, gate_sum);
    bucket_count_kernel<<<NB1, B, 0, stream>>>(rows, sidx, ghist, winner);
    gscan1_kernel<<<GB, 256, 0, stream>>>(ghist, bsum2, GN);
    gscan2_kernel<<<1, 1024, 0, stream>>>(bsum2, GB);
    gscan3_kernel<<<GB, 256, 0, stream>>>(ghist, bsum2, GN);
    bucket_scatter_kernel<<<NB1, B, 0, stream>>>(rows, cols, vals, winner, gate, ghist, buf);
    bucket_to_csr_kernel<<<NBUCKET, B, 0, stream>>>(ghist, buf, rowptr, edata);

    spmm_packed_kernel<<<grid_spmm, B, 0, stream>>>(rowptr, edata, z0, z1);
    spmm_packed_kernel<<<grid_spmm, B, 0, stream>>>(rowptr, edata, z1, z2);
    spmm_final_kernel<<<grid_spmm, B, 0, stream>>>(rowptr, edata, z2, z1, z2,
                                                   user, item, outx, outy);

    final_kernel<<<1, 64, 0, stream>>>(gate_sum, out_scalar);
}

// Round 5
// 475.162 us; speedup vs baseline: 1.8020x; 1.0592x over previous
//
#include <hip/hip_runtime.h>
#include <math.h>

#define NUM_USERS 100000
#define NUM_ITEMS 50000
#define NN 150000
#define DD 64
#define EE 1250000
#define SS 400000
#define TAU 0.2f
#define EDGE_BIAS 0.5f

#define NBUCKET 586     // coarse buckets (row >> 8)
#define NB1 153         // partition blocks
#define TILE 8192       // edges per partition block (153*8192 >= EE)
#define GN (NBUCKET * NB1)        // 89658 ghist entries
#define GB ((GN + 255) / 256)     // 351 scan blocks

typedef __attribute__((ext_vector_type(8))) _Float16 f16x8;
typedef __attribute__((ext_vector_type(2))) _Float16 f16x2;
typedef __attribute__((ext_vector_type(4))) float f32x4;

#define LDW 136  // f16 LDS row stride for gate W1 prologue

// bf16 helpers (RNE, finite inputs)
__device__ __forceinline__ unsigned int pack_bf16(float lo, float hi) {
    unsigned int a = __float_as_uint(lo), b = __float_as_uint(hi);
    a += 0x7fffu + ((a >> 16) & 1u);
    b += 0x7fffu + ((b >> 16) & 1u);
    return (a >> 16) | (b & 0xffff0000u);
}
__device__ __forceinline__ float bf_lo(unsigned int u) { return __uint_as_float(u << 16); }
__device__ __forceinline__ float bf_hi(unsigned int u) { return __uint_as_float(u & 0xffff0000u); }

// ---------------------------------------------------------------------------
// init: z0 is HALF-width (128B/row): at layer 0 both chains are identical,
// so one packed half serves both lane groups in spmm pass 1 (halves the
// pass-1 gather volume). Also f16 ego copy for gate, winner=-1, rowptr[NN],
// gate_sum=0.
// ---------------------------------------------------------------------------
__global__ void init_kernel(const float* __restrict__ user, const float* __restrict__ item,
                            unsigned int* __restrict__ z0h, _Float16* __restrict__ ego16,
                            int* __restrict__ winner, int* __restrict__ rowptr,
                            double* __restrict__ gate_sum) {
    int j = blockIdx.x * blockDim.x + threadIdx.x;
    if (j < NN * 32) {
        int n = j >> 5, dp = j & 31;
        const float* ego = (n < NUM_USERS) ? user + (size_t)n * 64
                                           : item + (size_t)(n - NUM_USERS) * 64;
        float2 e = *(const float2*)(ego + 2 * dp);
        z0h[j] = pack_bf16(e.x, e.y);
        f16x2 h;
        h[0] = (_Float16)e.x;
        h[1] = (_Float16)e.y;
        *(f16x2*)(ego16 + (size_t)n * 64 + 2 * dp) = h;
    }
    if (j < EE) winner[j] = -1;
    if (j == 0) { rowptr[NN] = EE; *gate_sum = 0.0; }
}

// ---------------------------------------------------------------------------
// gate MLP via f16 MFMA, barrier-free direct-gather, fast-math epilogue.
// R4 diagnosis: libm logf/log1pf/expf (~180 inst/edge) on 4/64 lanes was a
// serial divergent VALU tail. Replaced with hw v_log/v_exp/v_rcp (~12
// inst/edge). Precision: where 1-ev loses relative accuracy (ev->1), z/TAU
// is +-70 -> sigmoid saturated -> error doesn't propagate; mid-range exact.
// ---------------------------------------------------------------------------
__global__ __launch_bounds__(256) void gate_kernel(
        const _Float16* __restrict__ ego16,
        const int* __restrict__ rows, const int* __restrict__ cols,
        const int* __restrict__ sidx, const float* __restrict__ eps,
        const float* __restrict__ W1, const float* __restrict__ b1,
        const float* __restrict__ W2, const float* __restrict__ b2,
        float* __restrict__ gate, double* __restrict__ gate_sum) {
    __shared__ _Float16 sh[64 * LDW];
    __shared__ double sdq[4];

    const int t    = threadIdx.x;
    const int lane = t & 63;
    const int w    = t >> 6;
    const int col  = lane & 15;
    const int quad = lane >> 4;

    // prologue: stage W1 transposed, build B-fragments, then LDS is dead
    for (int idx = t; idx < 8192; idx += 256) {
        int k = idx >> 6, n = idx & 63;
        sh[n * LDW + k] = (_Float16)W1[idx];
    }
    float b1v[4];
#pragma unroll
    for (int nt = 0; nt < 4; ++nt) b1v[nt] = b1[nt * 16 + col];
    float w2v[4];
#pragma unroll
    for (int nt = 0; nt < 4; ++nt) w2v[nt] = W2[nt * 16 + col];
    const float b2v = b2[0];
    __syncthreads();

    f16x8 bfrag[4][4];
#pragma unroll
    for (int nt = 0; nt < 4; ++nt)
#pragma unroll
        for (int kk = 0; kk < 4; ++kk)
            bfrag[nt][kk] = *(const f16x8*)&sh[(nt * 16 + col) * LDW + kk * 32 + quad * 8];

    double partial = 0.0;
    const int nwaves = gridDim.x * 4;
    const int wid = blockIdx.x * 4 + w;

    for (int grp = wid; grp < SS / 16; grp += nwaves) {
        const int gbase = grp * 16;
        const int sid = sidx[gbase + col];
        const int su = rows[sid];
        const int sv = cols[sid];
        const _Float16* pu = ego16 + (size_t)su * 64 + quad * 8;
        const _Float16* pv = ego16 + (size_t)sv * 64 + quad * 8;
        f16x8 a0 = *(const f16x8*)(pu);
        f16x8 a1 = *(const f16x8*)(pu + 32);
        f16x8 a2 = *(const f16x8*)(pv);
        f16x8 a3 = *(const f16x8*)(pv + 32);

        f32x4 acc[4] = {};
#pragma unroll
        for (int nt = 0; nt < 4; ++nt) {
            acc[nt] = __builtin_amdgcn_mfma_f32_16x16x32_f16(a0, bfrag[nt][0], acc[nt], 0, 0, 0);
            acc[nt] = __builtin_amdgcn_mfma_f32_16x16x32_f16(a1, bfrag[nt][1], acc[nt], 0, 0, 0);
            acc[nt] = __builtin_amdgcn_mfma_f32_16x16x32_f16(a2, bfrag[nt][2], acc[nt], 0, 0, 0);
            acc[nt] = __builtin_amdgcn_mfma_f32_16x16x32_f16(a3, bfrag[nt][3], acc[nt], 0, 0, 0);
        }

        float p[4];
#pragma unroll
        for (int r = 0; r < 4; ++r) {
            float sum = 0.f;
#pragma unroll
            for (int nt = 0; nt < 4; ++nt)
                sum = fmaf(fmaxf(acc[nt][r] + b1v[nt], 0.f), w2v[nt], sum);
#pragma unroll
            for (int off = 8; off >= 1; off >>= 1) sum += __shfl_xor(sum, off);
            p[r] = sum + b2v;   // edge gbase + quad*4 + r
        }
        if (col == 0) {
            const int sb = gbase + quad * 4;
            float4 ev4 = *(const float4*)(eps + sb);
            float g4[4];
            const float evs[4] = {ev4.x, ev4.y, ev4.z, ev4.w};
#pragma unroll
            for (int r = 0; r < 4; ++r) {
                float ev  = evs[r] * (1.f - 2e-6f) + 1e-6f;
                float gum = __logf(ev) - __logf(1.f - ev);
                float zz  = (p[r] + gum) * (1.f / TAU);
                float g   = __builtin_amdgcn_rcpf(1.f + __expf(-zz)) + EDGE_BIAS;
                g4[r] = g;
                partial += (double)g;
            }
            *(float4*)(gate + sb) = make_float4(g4[0], g4[1], g4[2], g4[3]);
        }
    }

#pragma unroll
    for (int off = 32; off >= 1; off >>= 1) partial += __shfl_xor(partial, off);
    if (lane == 0) sdq[w] = partial;
    __syncthreads();
    if (t == 0) atomicAdd(gate_sum, sdq[0] + sdq[1] + sdq[2] + sdq[3]);
}

// ---------------------------------------------------------------------------
// Deterministic radix-partition scatter (unchanged from round 3)
// ---------------------------------------------------------------------------
__global__ __launch_bounds__(256) void bucket_count_kernel(
        const int* __restrict__ rows, const int* __restrict__ sidx,
        int* __restrict__ ghist, int* __restrict__ winner) {
    __shared__ int h[NBUCKET];
    const int t = threadIdx.x;
    for (int i = t; i < NBUCKET; i += 256) h[i] = 0;
    __syncthreads();
    const int base = blockIdx.x * TILE;
    const int end = (base + TILE < EE) ? base + TILE : EE;
    for (int i = base + t; i < end; i += 256) atomicAdd(&h[rows[i] >> 8], 1);
    const int gt = blockIdx.x * 256 + t;
    for (int s = gt; s < SS; s += NB1 * 256) atomicMax(&winner[sidx[s]], s);
    __syncthreads();
    for (int i = t; i < NBUCKET; i += 256) ghist[i * NB1 + blockIdx.x] = h[i];
}

__global__ void gscan1_kernel(int* __restrict__ data, int* __restrict__ bsum, int N) {
    __shared__ int sh[256];
    int tid = threadIdx.x;
    int i = blockIdx.x * 256 + tid;
    int v = (i < N) ? data[i] : 0;
    sh[tid] = v;
    __syncthreads();
    for (int off = 1; off < 256; off <<= 1) {
        int tv = (tid >= off) ? sh[tid - off] : 0;
        __syncthreads();
        sh[tid] += tv;
        __syncthreads();
    }
    if (i < N) data[i] = sh[tid] - v;
    if (tid == 255) bsum[blockIdx.x] = sh[255];
}

__global__ void gscan2_kernel(int* __restrict__ bsum, int NB) {
    __shared__ int sh[1024];
    int tid = threadIdx.x;
    int v = (tid < NB) ? bsum[tid] : 0;
    sh[tid] = v;
    __syncthreads();
    for (int off = 1; off < 1024; off <<= 1) {
        int tv = (tid >= off) ? sh[tid - off] : 0;
        __syncthreads();
        sh[tid] += tv;
        __syncthreads();
    }
    if (tid < NB) bsum[tid] = sh[tid] - v;
}

__global__ void gscan3_kernel(int* __restrict__ data, const int* __restrict__ bsum, int N) {
    int i = blockIdx.x * blockDim.x + threadIdx.x;
    if (i < N) data[i] += bsum[i >> 8];
}

__global__ __launch_bounds__(256) void bucket_scatter_kernel(
        const int* __restrict__ rows, const int* __restrict__ cols,
        const float* __restrict__ vals,
        const int* __restrict__ winner, const float* __restrict__ gate,
        const int* __restrict__ ghist, int4* __restrict__ buf) {
    __shared__ int sbase[NBUCKET];
    const int t = threadIdx.x;
    for (int i = t; i < NBUCKET; i += 256) sbase[i] = ghist[i * NB1 + blockIdx.x];
    __syncthreads();
    const int base = blockIdx.x * TILE;
    const int end = (base + TILE < EE) ? base + TILE : EE;
    for (int e = base + t; e < end; e += 256) {
        int r = rows[e];
        float v = vals[e];
        int wn = winner[e];
        float mv = (wn >= 0) ? v * gate[wn] : v;
        int pos = atomicAdd(&sbase[r >> 8], 1);
        buf[pos] = make_int4(r, cols[e], __float_as_int(v), __float_as_int(mv));
    }
}

__global__ __launch_bounds__(256) void bucket_to_csr_kernel(
        const int* __restrict__ ghist, const int4* __restrict__ buf,
        int* __restrict__ rowptr, int4* __restrict__ edata) {
    __shared__ int sh[256];
    const int b = blockIdx.x;
    const int t = threadIdx.x;
    const int rbeg = ghist[b * NB1];
    const int rend = (b + 1 < NBUCKET) ? ghist[(b + 1) * NB1] : EE;
    sh[t] = 0;
    __syncthreads();
    for (int i = rbeg + t; i < rend; i += 256) atomicAdd(&sh[buf[i].x & 255], 1);
    __syncthreads();
    int cnt = sh[t];
    for (int off = 1; off < 256; off <<= 1) {
        int tv = (t >= off) ? sh[t - off] : 0;
        __syncthreads();
        sh[t] += tv;
        __syncthreads();
    }
    int rowbase = rbeg + sh[t] - cnt;
    int r = (b << 8) + t;
    if (r < NN) rowptr[r] = rowbase;
    __syncthreads();
    sh[t] = rowbase;
    __syncthreads();
    for (int i = rbeg + t; i < rend; i += 256) {
        int4 ed = buf[i];
        int pos = atomicAdd(&sh[ed.x & 255], 1);
        edata[pos] = make_int4(ed.y, ed.z, ed.w, 0);
    }
}

// ---------------------------------------------------------------------------
// packed dual-chain gather-SpMM, dwordx4 layout. zstride/zmask parametrize
// the source row width: pass 1 uses the half-width z0 (stride 32, mask 7 —
// both chain lane-groups read the same 128B since chains are equal at l=0);
// later passes use full 256B rows (stride 64, mask 15).
// ---------------------------------------------------------------------------
__global__ __launch_bounds__(256) void spmm_packed_kernel(
        const int* __restrict__ rowptr, const int4* __restrict__ edata,
        const unsigned int* __restrict__ zin, unsigned int* __restrict__ zout,
        int zstride, int zmask) {
    int w = (blockIdx.x * blockDim.x + threadIdx.x) >> 6;
    if (w >= NN) return;
    const int lane = threadIdx.x & 63;
    const int g    = lane >> 4;
    const int sub  = lane & 15;
    const int sq   = (sub & zmask) * 4;
    const int beg = rowptr[w], end = rowptr[w + 1];

    float a[8] = {0.f, 0.f, 0.f, 0.f, 0.f, 0.f, 0.f, 0.f};
    int i = beg;
    for (; i + 8 <= end; i += 8) {
        int4 e0 = edata[i + g];
        int4 e1 = edata[i + 4 + g];
        uint4 p0 = *(const uint4*)(zin + (size_t)e0.x * zstride + sq);
        uint4 p1 = *(const uint4*)(zin + (size_t)e1.x * zstride + sq);
        float w0 = (sub < 8) ? __int_as_float(e0.y) : __int_as_float(e0.z);
        float w1 = (sub < 8) ? __int_as_float(e1.y) : __int_as_float(e1.z);
        a[0] = fmaf(w0, bf_lo(p0.x), a[0]); a[1] = fmaf(w0, bf_hi(p0.x), a[1]);
        a[2] = fmaf(w0, bf_lo(p0.y), a[2]); a[3] = fmaf(w0, bf_hi(p0.y), a[3]);
        a[4] = fmaf(w0, bf_lo(p0.z), a[4]); a[5] = fmaf(w0, bf_hi(p0.z), a[5]);
        a[6] = fmaf(w0, bf_lo(p0.w), a[6]); a[7] = fmaf(w0, bf_hi(p0.w), a[7]);
        a[0] = fmaf(w1, bf_lo(p1.x), a[0]); a[1] = fmaf(w1, bf_hi(p1.x), a[1]);
        a[2] = fmaf(w1, bf_lo(p1.y), a[2]); a[3] = fmaf(w1, bf_hi(p1.y), a[3]);
        a[4] = fmaf(w1, bf_lo(p1.z), a[4]); a[5] = fmaf(w1, bf_hi(p1.z), a[5]);
        a[6] = fmaf(w1, bf_lo(p1.w), a[6]); a[7] = fmaf(w1, bf_hi(p1.w), a[7]);
    }
    for (; i < end; i += 4) {
        int idx = i + g;
        int4 e = edata[(idx < end) ? idx : end - 1];
        float wt = (idx < end) ? ((sub < 8) ? __int_as_float(e.y) : __int_as_float(e.z)) : 0.f;
        uint4 p = *(const uint4*)(zin + (size_t)e.x * zstride + sq);
        a[0] = fmaf(wt, bf_lo(p.x), a[0]); a[1] = fmaf(wt, bf_hi(p.x), a[1]);
        a[2] = fmaf(wt, bf_lo(p.y), a[2]); a[3] = fmaf(wt, bf_hi(p.y), a[3]);
        a[4] = fmaf(wt, bf_lo(p.z), a[4]); a[5] = fmaf(wt, bf_hi(p.z), a[5]);
        a[6] = fmaf(wt, bf_lo(p.w), a[6]); a[7] = fmaf(wt, bf_hi(p.w), a[7]);
    }
#pragma unroll
    for (int j = 0; j < 8; ++j) {
        a[j] += __shfl_xor(a[j], 16);
        a[j] += __shfl_xor(a[j], 32);
    }
    if (lane < 16) {
        uint4 o;
        o.x = pack_bf16(a[0], a[1]);
        o.y = pack_bf16(a[2], a[3]);
        o.z = pack_bf16(a[4], a[5]);
        o.w = pack_bf16(a[6], a[7]);
        *(uint4*)(zout + (size_t)w * 64 + sub * 4) = o;
    }
}

// ---------------------------------------------------------------------------
// final SpMM layer fused with fold (unchanged from round 4)
// ---------------------------------------------------------------------------
__global__ __launch_bounds__(256) void spmm_final_kernel(
        const int* __restrict__ rowptr, const int4* __restrict__ edata,
        const unsigned int* __restrict__ zin,
        const unsigned int* __restrict__ z1, const unsigned int* __restrict__ z2,
        const float* __restrict__ user, const float* __restrict__ item,
        float* __restrict__ outx, float* __restrict__ outy) {
    int w = (blockIdx.x * blockDim.x + threadIdx.x) >> 6;
    if (w >= NN) return;
    const int lane = threadIdx.x & 63;
    const int g    = lane >> 4;
    const int sub  = lane & 15;
    const int beg = rowptr[w], end = rowptr[w + 1];

    float a[8] = {0.f, 0.f, 0.f, 0.f, 0.f, 0.f, 0.f, 0.f};
    int i = beg;
    for (; i + 8 <= end; i += 8) {
        int4 e0 = edata[i + g];
        int4 e1 = edata[i + 4 + g];
        uint4 p0 = *(const uint4*)(zin + (size_t)e0.x * 64 + sub * 4);
        uint4 p1 = *(const uint4*)(zin + (size_t)e1.x * 64 + sub * 4);
        float w0 = (sub < 8) ? __int_as_float(e0.y) : __int_as_float(e0.z);
        float w1 = (sub < 8) ? __int_as_float(e1.y) : __int_as_float(e1.z);
        a[0] = fmaf(w0, bf_lo(p0.x), a[0]); a[1] = fmaf(w0, bf_hi(p0.x), a[1]);
        a[2] = fmaf(w0, bf_lo(p0.y), a[2]); a[3] = fmaf(w0, bf_hi(p0.y), a[3]);
        a[4] = fmaf(w0, bf_lo(p0.z), a[4]); a[5] = fmaf(w0, bf_hi(p0.z), a[5]);
        a[6] = fmaf(w0, bf_lo(p0.w), a[6]); a[7] = fmaf(w0, bf_hi(p0.w), a[7]);
        a[0] = fmaf(w1, bf_lo(p1.x), a[0]); a[1] = fmaf(w1, bf_hi(p1.x), a[1]);
        a[2] = fmaf(w1, bf_lo(p1.y), a[2]); a[3] = fmaf(w1, bf_hi(p1.y), a[3]);
        a[4] = fmaf(w1, bf_lo(p1.z), a[4]); a[5] = fmaf(w1, bf_hi(p1.z), a[5]);
        a[6] = fmaf(w1, bf_lo(p1.w), a[6]); a[7] = fmaf(w1, bf_hi(p1.w), a[7]);
    }
    for (; i < end; i += 4) {
        int idx = i + g;
        int4 e = edata[(idx < end) ? idx : end - 1];
        float wt = (idx < end) ? ((sub < 8) ? __int_as_float(e.y) : __int_as_float(e.z)) : 0.f;
        uint4 p = *(const uint4*)(zin + (size_t)e.x * 64 + sub * 4);
        a[0] = fmaf(wt, bf_lo(p.x), a[0]); a[1] = fmaf(wt, bf_hi(p.x), a[1]);
        a[2] = fmaf(wt, bf_lo(p.y), a[2]); a[3] = fmaf(wt, bf_hi(p.y), a[3]);
        a[4] = fmaf(wt, bf_lo(p.z), a[4]); a[5] = fmaf(wt, bf_hi(p.z), a[5]);
        a[6] = fmaf(wt, bf_lo(p.w), a[6]); a[7] = fmaf(wt, bf_hi(p.w), a[7]);
    }
#pragma unroll
    for (int j = 0; j < 8; ++j) {
        a[j] += __shfl_xor(a[j], 16);
        a[j] += __shfl_xor(a[j], 32);
    }
    if (lane < 16) {
        uint4 u1 = *(const uint4*)(z1 + (size_t)w * 64 + sub * 4);
        uint4 u2 = *(const uint4*)(z2 + (size_t)w * 64 + sub * 4);
        const float* eg = (w < NUM_USERS) ? user + (size_t)w * 64
                                          : item + (size_t)(w - NUM_USERS) * 64;
        eg += 8 * (sub & 7);
        float4 e0 = *(const float4*)(eg);
        float4 e1 = *(const float4*)(eg + 4);
        float4 o0, o1;
        o0.x = (e0.x + bf_lo(u1.x) + bf_lo(u2.x) + a[0]) * 0.25f;
        o0.y = (e0.y + bf_hi(u1.x) + bf_hi(u2.x) + a[1]) * 0.25f;
        o0.z = (e0.z + bf_lo(u1.y) + bf_lo(u2.y) + a[2]) * 0.25f;
        o0.w = (e0.w + bf_hi(u1.y) + bf_hi(u2.y) + a[3]) * 0.25f;
        o1.x = (e1.x + bf_lo(u1.z) + bf_lo(u2.z) + a[4]) * 0.25f;
        o1.y = (e1.y + bf_hi(u1.z) + bf_hi(u2.z) + a[5]) * 0.25f;
        o1.z = (e1.z + bf_lo(u1.w) + bf_lo(u2.w) + a[6]) * 0.25f;
        o1.w = (e1.w + bf_hi(u1.w) + bf_hi(u2.w) + a[7]) * 0.25f;
        float* dst = ((sub < 8) ? outx : outy) + (size_t)w * 64 + 8 * (sub & 7);
        *(float4*)dst = o0;
        *(float4*)(dst + 4) = o1;
    }
}

__global__ void final_kernel(const double* __restrict__ gate_sum, float* __restrict__ out_scalar) {
    if (threadIdx.x == 0) out_scalar[0] = (float)(*gate_sum * (1.0 / (double)SS));
}

extern "C" void kernel_launch(void* const* d_in, const int* in_sizes, int n_in,
                              void* d_out, int out_size, void* d_ws, size_t ws_size,
                              hipStream_t stream) {
    const float* user = (const float*)d_in[0];
    const float* item = (const float*)d_in[1];
    const int*   rows = (const int*)d_in[2];
    const int*   cols = (const int*)d_in[3];
    const float* vals = (const float*)d_in[4];
    const int*   sidx = (const int*)d_in[5];
    const float* eps  = (const float*)d_in[6];
    const float* W1   = (const float*)d_in[7];
    const float* b1   = (const float*)d_in[8];
    const float* W2   = (const float*)d_in[9];
    const float* b2   = (const float*)d_in[10];

    float* out  = (float*)d_out;
    const size_t ND = (size_t)NN * DD;
    float* outx = out;
    float* outy = out + ND;
    float* out_scalar = out + 2 * ND;

    unsigned int* wsu = (unsigned int*)d_ws;
    unsigned int* z0 = wsu;          // half-width: NN*32 used (region sized ND)
    unsigned int* z1 = wsu + ND;
    unsigned int* z2 = wsu + 2 * ND;
    int4* edata = (int4*)(wsu + 3 * ND);
    // ego16 (19.2 MB) aliases edata (20 MB): live init->gate; edata written
    // only by bucket_to_csr (after gate completes, same stream).
    _Float16* ego16 = (_Float16*)edata;
    // buf (20 MB) aliases z1 (38.4 MB): live scatter->to_csr; z1 first
    // written by spmm #1, after to_csr completes.
    int4* buf = (int4*)z1;
    unsigned int* regionA = wsu + 3 * ND + (size_t)EE * 4;
    int*   rowptr = (int*)regionA;                    // [0, 150016)
    float* gate   = (float*)(regionA + 150016);       // SS floats
    int*   ghist  = (int*)(regionA + 550016);         // GN = 89658 ints
    int*   bsum2  = (int*)(regionA + 639680);         // GB = 351 ints
    int*   winner = (int*)(regionA + 640032);         // EE ints
    double* gate_sum = (double*)(((uintptr_t)(regionA + 640032 + EE) + 7) & ~(uintptr_t)7);

    const int B = 256;
    const int grid_init = (int)((NN * 32 + B - 1) / B);
    const int grid_E    = (EE + B - 1) / B;
    const int grid_spmm = (int)((NN * 64 + B - 1) / B);
    // init also covers winner (EE) via its j-range: need max(NN*32, EE)
    const int grid_init2 = (grid_E > grid_init) ? grid_E : grid_init;

    init_kernel<<<grid_init2, B, 0, stream>>>(user, item, z0, ego16, winner, rowptr, gate_sum);
    gate_kernel<<<2048, B, 0, stream>>>(ego16, rows, cols, sidx, eps,
                                        W1, b1, W2, b2, gate, gate_sum);
    bucket_count_kernel<<<NB1, B, 0, stream>>>(rows, sidx, ghist, winner);
    gscan1_kernel<<<GB, 256, 0, stream>>>(ghist, bsum2, GN);
    gscan2_kernel<<<1, 1024, 0, stream>>>(bsum2, GB);
    gscan3_kernel<<<GB, 256, 0, stream>>>(ghist, bsum2, GN);
    bucket_scatter_kernel<<<NB1, B, 0, stream>>>(rows, cols, vals, winner, gate, ghist, buf);
    bucket_to_csr_kernel<<<NBUCKET, B, 0, stream>>>(ghist, buf, rowptr, edata);

    spmm_packed_kernel<<<grid_spmm, B, 0, stream>>>(rowptr, edata, z0, z1, 32, 7);
    spmm_packed_kernel<<<grid_spmm, B, 0, stream>>>(rowptr, edata, z1, z2, 64, 15);
    spmm_final_kernel<<<grid_spmm, B, 0, stream>>>(rowptr, edata, z2, z1, z2,
                                                   user, item, outx, outy);

    final_kernel<<<1, 64, 0, stream>>>(gate_sum, out_scalar);
}